// Round 10
// baseline (359.466 us; speedup 1.0000x reference)
//
#include <hip/hip_runtime.h>
#include <math.h>

// ---------------- helpers ----------------
typedef short short8 __attribute__((ext_vector_type(8)));
typedef float floatx4 __attribute__((ext_vector_type(4)));

__device__ __forceinline__ float4 ld4(const float* p) { return *reinterpret_cast<const float4*>(p); }
__device__ __forceinline__ void st4(float* p, float4 v) { *reinterpret_cast<float4*>(p) = v; }

__device__ __forceinline__ float bf2f(unsigned int u) { return __uint_as_float(u << 16); }
__device__ __forceinline__ unsigned int f2bf1(float f) {
    unsigned int x = __float_as_uint(f);
    return (x + 0x7fffu + ((x >> 16) & 1u)) >> 16;  // RNE
}
__device__ __forceinline__ unsigned int f2bf2(float lo, float hi) {
    return f2bf1(lo) | (f2bf1(hi) << 16);
}
__device__ __forceinline__ void unpack8(uint4 v, float* f) {
    f[0] = bf2f(v.x & 0xffffu); f[1] = bf2f(v.x >> 16);
    f[2] = bf2f(v.y & 0xffffu); f[3] = bf2f(v.y >> 16);
    f[4] = bf2f(v.z & 0xffffu); f[5] = bf2f(v.z >> 16);
    f[6] = bf2f(v.w & 0xffffu); f[7] = bf2f(v.w >> 16);
}

// ---------------- launch A: edge count/rank + all-W transpose ----------------
__global__ __launch_bounds__(256) void k_count_prep(const int* __restrict__ dst, int* __restrict__ deg,
                                                    int* __restrict__ rank, int E, int nbE,
                                                    const float* __restrict__ W1, const float* __restrict__ W2,
                                                    const float* __restrict__ W3, unsigned short* __restrict__ Wt1,
                                                    unsigned short* __restrict__ Wt2, unsigned short* __restrict__ Wt3) {
    if ((int)blockIdx.x < nbE) {
        int e = blockIdx.x * 256 + threadIdx.x;
        if (e < E) rank[e] = atomicAdd(&deg[dst[e]], 1);
    } else {
        int t = (blockIdx.x - nbE) * 256 + threadIdx.x;
        if (t < 16384) {
            int k = t & 127, n = t >> 7;
            Wt1[n * 128 + k] = (unsigned short)f2bf1(W1[(size_t)k * 128 + n]);
        } else if (t < 32768) {
            int u = t - 16384;
            int k = u & 127, n = u >> 7;
            Wt2[n * 128 + k] = (unsigned short)f2bf1(W2[(size_t)k * 128 + n]);
        } else if (t < 40960) {
            int u = t - 32768;
            int k = u & 127, n = u >> 7;
            Wt3[n * 128 + k] = (unsigned short)f2bf1(W3[(size_t)k * 64 + n]);
        }
    }
}

// ---------------- launch B: single-block full scan (block 0) + layer-1 MFMA GEMM (blocks 1..) ----------------
// Scan: 256 threads, ~196 elems/thread: serial sum -> Hillis-Steele block scan -> row_off + dinv.
// gemm1: as before (x f32 -> bf16 staging), row0 = (blockIdx.x-1)*64.
__global__ __launch_bounds__(256) void k_scan_gemm1(const int* __restrict__ deg, int* __restrict__ row_off,
                                                    float* __restrict__ dinv, int n,
                                                    const float* __restrict__ X, const unsigned short* __restrict__ Wt,
                                                    unsigned short* __restrict__ O, int nrows) {
    constexpr int LDR = 136;
    __shared__ __align__(16) unsigned char smem[(64 * LDR + 128 * LDR) * 2];  // 52224 B

    const int tid = threadIdx.x;
    if (blockIdx.x == 0) {
        int* s = (int*)smem;
        int per = (n + 255) / 256;
        int start = tid * per;
        int end   = start + per; if (end > n) end = n;
        int sum = 0;
        for (int i = start; i < end; ++i) sum += deg[i];
        s[tid] = sum;
        __syncthreads();
        int incl = sum;
        for (int off = 1; off < 256; off <<= 1) {
            int x = (tid >= off) ? s[tid - off] : 0;
            __syncthreads();
            incl += x;
            s[tid] = incl;
            __syncthreads();
        }
        int run = incl - sum;  // exclusive prefix
        for (int i = start; i < end; ++i) {
            int d = deg[i];
            row_off[i] = run;
            dinv[i]    = 1.0f / sqrtf((float)d + 1.0f);
            run += d;
        }
        if (start < n && end == n) row_off[n] = run;
        return;
    }

    unsigned short* sX = (unsigned short*)smem;
    unsigned short* sB = sX + 64 * LDR;
    const int row0 = ((int)blockIdx.x - 1) * 64;

#pragma unroll
    for (int i = 0; i < 4; ++i) {
        int idx = tid + i * 256;
        int r = idx >> 4, c8 = idx & 15;
        int grow = row0 + r;
        uint4 v = make_uint4(0, 0, 0, 0);
        if (grow < nrows) {
            float4 a = ld4(X + (size_t)grow * 128 + c8 * 8);
            float4 b = ld4(X + (size_t)grow * 128 + c8 * 8 + 4);
            v = make_uint4(f2bf2(a.x, a.y), f2bf2(a.z, a.w), f2bf2(b.x, b.y), f2bf2(b.z, b.w));
        }
        *reinterpret_cast<uint4*>(&sX[r * LDR + c8 * 8]) = v;
    }
#pragma unroll
    for (int i = 0; i < 8; ++i) {
        int idx = tid + i * 256;
        int nn = idx >> 4, c8 = idx & 15;
        *reinterpret_cast<uint4*>(&sB[nn * LDR + c8 * 8]) =
            *reinterpret_cast<const uint4*>(Wt + (size_t)nn * 128 + c8 * 8);
    }
    __syncthreads();

    const int lane = tid & 63;
    const int wave = tid >> 6;
    const int l15  = lane & 15;
    const int quad = lane >> 4;

    floatx4 acc[8];
#pragma unroll
    for (int j = 0; j < 8; ++j) acc[j] = (floatx4){0.f, 0.f, 0.f, 0.f};

    const unsigned short* xbase = &sX[(wave * 16 + l15) * LDR + quad * 8];
#pragma unroll
    for (int kk = 0; kk < 4; ++kk) {
        short8 xb = *reinterpret_cast<const short8*>(xbase + kk * 32);
#pragma unroll
        for (int j = 0; j < 8; ++j) {
            short8 wa = *reinterpret_cast<const short8*>(&sB[(j * 16 + l15) * LDR + quad * 8 + kk * 32]);
            acc[j] = __builtin_amdgcn_mfma_f32_16x16x32_bf16(wa, xb, acc[j], 0, 0, 0);
        }
    }

    int xrow = row0 + wave * 16 + l15;
    if (xrow < nrows) {
#pragma unroll
        for (int j = 0; j < 8; ++j) {
            uint2 o = make_uint2(f2bf2(acc[j][0], acc[j][1]), f2bf2(acc[j][2], acc[j][3]));
            *reinterpret_cast<uint2*>(O + (size_t)xrow * 128 + j * 16 + quad * 4) = o;
        }
    }
}

// ---------------- launch C: CSR fill (4B scatter) + bufA *= dinv[row] scale ----------------
__global__ __launch_bounds__(256) void k_fill_scale(const int* __restrict__ src, const int* __restrict__ dst,
                                                    const int* __restrict__ rank, const int* __restrict__ roff,
                                                    int* __restrict__ csrc, int E, int nbE,
                                                    unsigned short* __restrict__ A, const float* __restrict__ dinv,
                                                    int n16) {
    if ((int)blockIdx.x < nbE) {
        int e = blockIdx.x * 256 + threadIdx.x;
        if (e < E) csrc[roff[dst[e]] + rank[e]] = src[e];
    } else {
        int idx = (blockIdx.x - nbE) * 256 + threadIdx.x;
        if (idx < n16) {
            float di = dinv[idx >> 4];
            uint4 v = *reinterpret_cast<const uint4*>(A + (size_t)idx * 8);
            float f[8];
            unpack8(v, f);
#pragma unroll
            for (int i = 0; i < 8; ++i) f[i] *= di;
            uint4 o = make_uint4(f2bf2(f[0], f[1]), f2bf2(f[2], f[3]), f2bf2(f[4], f[5]), f2bf2(f[6], f[7]));
            *reinterpret_cast<uint4*>(A + (size_t)idx * 8) = o;
        }
    }
}

// ---------------- MFMA GEMM (layers 2/3): O = (X @ W) * dinv[row], bf16 ----------------
template <int NC>
__global__ __launch_bounds__(256) void k_gemm_mfma(const unsigned short* __restrict__ X,
                                                   const unsigned short* __restrict__ Wt,
                                                   const float* __restrict__ dinv,
                                                   unsigned short* __restrict__ O, int nrows) {
    constexpr int LDR = 136;
    __shared__ unsigned short sX[64 * LDR];
    __shared__ unsigned short sB[NC * LDR];

    const int tid  = threadIdx.x;
    const int row0 = blockIdx.x * 64;

#pragma unroll
    for (int i = 0; i < 4; ++i) {
        int idx = tid + i * 256;
        int r = idx >> 4, c8 = idx & 15;
        int grow = row0 + r;
        uint4 v = make_uint4(0, 0, 0, 0);
        if (grow < nrows) v = *reinterpret_cast<const uint4*>(X + (size_t)grow * 128 + c8 * 8);
        *reinterpret_cast<uint4*>(&sX[r * LDR + c8 * 8]) = v;
    }
#pragma unroll
    for (int i = 0; i < NC / 16; ++i) {
        int idx = tid + i * 256;
        int n = idx >> 4, c8 = idx & 15;
        *reinterpret_cast<uint4*>(&sB[n * LDR + c8 * 8]) =
            *reinterpret_cast<const uint4*>(Wt + (size_t)n * 128 + c8 * 8);
    }
    __syncthreads();

    const int lane = tid & 63;
    const int wave = tid >> 6;
    const int l15  = lane & 15;
    const int quad = lane >> 4;

    floatx4 acc[NC / 16];
#pragma unroll
    for (int j = 0; j < NC / 16; ++j) acc[j] = (floatx4){0.f, 0.f, 0.f, 0.f};

    const unsigned short* xbase = &sX[(wave * 16 + l15) * LDR + quad * 8];
#pragma unroll
    for (int kk = 0; kk < 4; ++kk) {
        short8 xb = *reinterpret_cast<const short8*>(xbase + kk * 32);
#pragma unroll
        for (int j = 0; j < NC / 16; ++j) {
            short8 wa = *reinterpret_cast<const short8*>(&sB[(j * 16 + l15) * LDR + quad * 8 + kk * 32]);
            acc[j] = __builtin_amdgcn_mfma_f32_16x16x32_bf16(wa, xb, acc[j], 0, 0, 0);
        }
    }

    int xrow = row0 + wave * 16 + l15;
    if (xrow < nrows) {
        float di = dinv[xrow];
#pragma unroll
        for (int j = 0; j < NC / 16; ++j) {
            uint2 o = make_uint2(f2bf2(acc[j][0] * di, acc[j][1] * di), f2bf2(acc[j][2] * di, acc[j][3] * di));
            *reinterpret_cast<uint2*>(O + (size_t)xrow * NC + j * 16 + quad * 4) = o;
        }
    }
}

// ---------------- aggregation (128 feats, pre-scaled bf16 H') + bias + relu ----------------
// 16 lanes/node, 8 feats/lane; 4-deep gather batches with csrc software prefetch.
__global__ __launch_bounds__(256) void k_agg_relu(const unsigned short* __restrict__ H, const int* __restrict__ roff,
                                                  const int* __restrict__ csrc, const float* __restrict__ dinv,
                                                  const float* __restrict__ bias, unsigned short* __restrict__ O, int n) {
    int t    = blockIdx.x * 256 + threadIdx.x;
    int node = t >> 4;
    int f8   = (t & 15) * 8;
    if (node >= n) return;

    float a[8];
    {
        uint4 hv = *reinterpret_cast<const uint4*>(H + (size_t)node * 128 + f8);
        unpack8(hv, a);  // self term H'[node]
    }

    int e  = roff[node];
    int e1 = roff[node + 1];
    int nfull = (e1 - e) >> 2;

    if (nfull > 0) {
        int s[4];
#pragma unroll
        for (int u = 0; u < 4; ++u) s[u] = csrc[e + u];
        for (int b = 1; b < nfull; ++b) {
            uint4 v[4];
#pragma unroll
            for (int u = 0; u < 4; ++u) v[u] = *reinterpret_cast<const uint4*>(H + (size_t)s[u] * 128 + f8);
            int sn[4];
            int base = e + b * 4;
#pragma unroll
            for (int u = 0; u < 4; ++u) sn[u] = csrc[base + u];  // prefetch next batch
#pragma unroll
            for (int u = 0; u < 4; ++u) {
                float g[8];
                unpack8(v[u], g);
#pragma unroll
                for (int i = 0; i < 8; ++i) a[i] += g[i];
            }
#pragma unroll
            for (int u = 0; u < 4; ++u) s[u] = sn[u];
        }
        uint4 v[4];
#pragma unroll
        for (int u = 0; u < 4; ++u) v[u] = *reinterpret_cast<const uint4*>(H + (size_t)s[u] * 128 + f8);
#pragma unroll
        for (int u = 0; u < 4; ++u) {
            float g[8];
            unpack8(v[u], g);
#pragma unroll
            for (int i = 0; i < 8; ++i) a[i] += g[i];
        }
        e += nfull * 4;
    }
    for (; e < e1; ++e) {
        uint4 v0 = *reinterpret_cast<const uint4*>(H + (size_t)csrc[e] * 128 + f8);
        float g0[8];
        unpack8(v0, g0);
#pragma unroll
        for (int i = 0; i < 8; ++i) a[i] += g0[i];
    }

    float di = dinv[node];
    float4 b0 = ld4(bias + f8);
    float4 b1 = ld4(bias + f8 + 4);
    float bb[8] = {b0.x, b0.y, b0.z, b0.w, b1.x, b1.y, b1.z, b1.w};
#pragma unroll
    for (int i = 0; i < 8; ++i) a[i] = fmaxf(a[i] * di + bb[i], 0.0f);

    uint4 ov = make_uint4(f2bf2(a[0], a[1]), f2bf2(a[2], a[3]), f2bf2(a[4], a[5]), f2bf2(a[6], a[7]));
    *reinterpret_cast<uint4*>(O + (size_t)node * 128 + f8) = ov;
}

// ---------------- aggregation (64 feats, pre-scaled bf16 H') + bias + log_softmax ----------------
// 8 lanes/node, 8 feats/lane; 8-deep batches with csrc software prefetch.
__global__ __launch_bounds__(256) void k_agg_softmax(const unsigned short* __restrict__ H, const int* __restrict__ roff,
                                                     const int* __restrict__ csrc, const float* __restrict__ dinv,
                                                     const float* __restrict__ bias, float* __restrict__ O, int n) {
    int t    = blockIdx.x * 256 + threadIdx.x;
    int node = t >> 3;
    int f8   = (t & 7) * 8;
    if (node >= n) return;

    float a[8];
    {
        uint4 hv = *reinterpret_cast<const uint4*>(H + (size_t)node * 64 + f8);
        unpack8(hv, a);  // self term
    }

    int e  = roff[node];
    int e1 = roff[node + 1];
    int nfull = (e1 - e) >> 3;

    if (nfull > 0) {
        int s[8];
#pragma unroll
        for (int u = 0; u < 8; ++u) s[u] = csrc[e + u];
        for (int b = 1; b < nfull; ++b) {
            uint4 v[8];
#pragma unroll
            for (int u = 0; u < 8; ++u) v[u] = *reinterpret_cast<const uint4*>(H + (size_t)s[u] * 64 + f8);
            int sn[8];
            int base = e + b * 8;
#pragma unroll
            for (int u = 0; u < 8; ++u) sn[u] = csrc[base + u];
#pragma unroll
            for (int u = 0; u < 8; ++u) {
                float gg[8];
                unpack8(v[u], gg);
#pragma unroll
                for (int i = 0; i < 8; ++i) a[i] += gg[i];
            }
#pragma unroll
            for (int u = 0; u < 8; ++u) s[u] = sn[u];
        }
        uint4 v[8];
#pragma unroll
        for (int u = 0; u < 8; ++u) v[u] = *reinterpret_cast<const uint4*>(H + (size_t)s[u] * 64 + f8);
#pragma unroll
        for (int u = 0; u < 8; ++u) {
            float gg[8];
            unpack8(v[u], gg);
#pragma unroll
            for (int i = 0; i < 8; ++i) a[i] += gg[i];
        }
        e += nfull * 8;
    }
    for (; e < e1; ++e) {
        uint4 v0 = *reinterpret_cast<const uint4*>(H + (size_t)csrc[e] * 64 + f8);
        float g0[8];
        unpack8(v0, g0);
#pragma unroll
        for (int i = 0; i < 8; ++i) a[i] += g0[i];
    }

    float di = dinv[node];
    float4 b0 = ld4(bias + f8);
    float4 b1 = ld4(bias + f8 + 4);
    float bb[8] = {b0.x, b0.y, b0.z, b0.w, b1.x, b1.y, b1.z, b1.w};
    float v[8];
#pragma unroll
    for (int i = 0; i < 8; ++i) v[i] = a[i] * di + bb[i];

    float m = v[0];
#pragma unroll
    for (int i = 1; i < 8; ++i) m = fmaxf(m, v[i]);
    m = fmaxf(m, __shfl_xor(m, 1));
    m = fmaxf(m, __shfl_xor(m, 2));
    m = fmaxf(m, __shfl_xor(m, 4));

    float ssum = 0.0f;
#pragma unroll
    for (int i = 0; i < 8; ++i) ssum += expf(v[i] - m);
    ssum += __shfl_xor(ssum, 1);
    ssum += __shfl_xor(ssum, 2);
    ssum += __shfl_xor(ssum, 4);
    float ls = logf(ssum);

    float* op = O + (size_t)node * 64 + f8;
    st4(op, make_float4(v[0] - m - ls, v[1] - m - ls, v[2] - m - ls, v[3] - m - ls));
    st4(op + 4, make_float4(v[4] - m - ls, v[5] - m - ls, v[6] - m - ls, v[7] - m - ls));
}

// ---------------- launch ----------------
extern "C" void kernel_launch(void* const* d_in, const int* in_sizes, int n_in,
                              void* d_out, int out_size, void* d_ws, size_t ws_size,
                              hipStream_t stream) {
    const float* x  = (const float*)d_in[0];
    const int*   ei = (const int*)d_in[1];
    const float* W1 = (const float*)d_in[2];
    const float* b1 = (const float*)d_in[3];
    const float* W2 = (const float*)d_in[4];
    const float* b2 = (const float*)d_in[5];
    const float* W3 = (const float*)d_in[6];
    const float* b3 = (const float*)d_in[7];
    float* out = (float*)d_out;

    const int N = in_sizes[0] / 128;
    const int E = in_sizes[1] / 2;
    const int* src = ei;
    const int* dst = ei + E;

    char* ws = (char*)d_ws;
    size_t off = 0;
    auto alloc = [&](size_t bytes) -> char* {
        char* p = ws + off;
        off = (off + bytes + 255) & ~(size_t)255;
        return p;
    };
    int nbE = (E + 255) / 256;
    int blocks64 = (N + 63) / 64;
    int n16 = N * 16;
    int nbS = (n16 + 255) / 256;

    int*   deg     = (int*)alloc((size_t)N * 4);
    int*   row_off = (int*)alloc(((size_t)N + 1) * 4);
    float* dinv    = (float*)alloc((size_t)N * 4);
    int*   rank    = (int*)alloc((size_t)E * 4);
    int*   csrc    = (int*)alloc((size_t)E * 4);
    unsigned short* Wt1  = (unsigned short*)alloc(128 * 128 * 2);
    unsigned short* Wt2  = (unsigned short*)alloc(128 * 128 * 2);
    unsigned short* Wt3  = (unsigned short*)alloc(64 * 128 * 2);
    unsigned short* bufA = (unsigned short*)alloc((size_t)N * 128 * 2);
    unsigned short* bufB = (unsigned short*)alloc((size_t)N * 128 * 2);
    unsigned short* bufC = (unsigned short*)alloc((size_t)N * 64 * 2);
    (void)ws_size; (void)n_in; (void)out_size;

    hipMemsetAsync(deg, 0, (size_t)N * 4, stream);
    // A: edge count/rank + W transposes (independent)
    k_count_prep<<<nbE + 160, 256, 0, stream>>>(dst, deg, rank, E, nbE, W1, W2, W3, Wt1, Wt2, Wt3);
    // B: single-block scan (row_off + dinv) + layer-1 GEMM
    k_scan_gemm1<<<1 + blocks64, 256, 0, stream>>>(deg, row_off, dinv, N, x, Wt1, bufA, N);
    // C: CSR fill (4B) + bufA *= dinv
    k_fill_scale<<<nbE + nbS, 256, 0, stream>>>(src, dst, rank, row_off, csrc, E, nbE, bufA, dinv, n16);

    // layer 1 aggregation (pre-scaled bufA)
    k_agg_relu<<<((size_t)N * 16 + 255) / 256, 256, 0, stream>>>(bufA, row_off, csrc, dinv, b1, bufB, N);
    // layer 2 (epilogue scales by dinv)
    k_gemm_mfma<128><<<blocks64, 256, 0, stream>>>(bufB, Wt2, dinv, bufA, N);
    k_agg_relu<<<((size_t)N * 16 + 255) / 256, 256, 0, stream>>>(bufA, row_off, csrc, dinv, b2, bufB, N);
    // layer 3 + log_softmax
    k_gemm_mfma<64><<<blocks64, 256, 0, stream>>>(bufB, Wt3, dinv, bufC, N);
    k_agg_softmax<<<((size_t)N * 8 + 255) / 256, 256, 0, stream>>>(bufC, row_off, csrc, dinv, b3, out, N);
}

// Round 11
// 254.742 us; speedup vs baseline: 1.4111x; 1.4111x over previous
//
#include <hip/hip_runtime.h>
#include <math.h>

// ---------------- helpers ----------------
typedef short short8 __attribute__((ext_vector_type(8)));
typedef float floatx4 __attribute__((ext_vector_type(4)));

__device__ __forceinline__ float4 ld4(const float* p) { return *reinterpret_cast<const float4*>(p); }
__device__ __forceinline__ void st4(float* p, float4 v) { *reinterpret_cast<float4*>(p) = v; }

__device__ __forceinline__ float bf2f(unsigned int u) { return __uint_as_float(u << 16); }
__device__ __forceinline__ unsigned int f2bf1(float f) {
    unsigned int x = __float_as_uint(f);
    return (x + 0x7fffu + ((x >> 16) & 1u)) >> 16;  // RNE
}
__device__ __forceinline__ unsigned int f2bf2(float lo, float hi) {
    return f2bf1(lo) | (f2bf1(hi) << 16);
}
__device__ __forceinline__ void unpack8(uint4 v, float* f) {
    f[0] = bf2f(v.x & 0xffffu); f[1] = bf2f(v.x >> 16);
    f[2] = bf2f(v.y & 0xffffu); f[3] = bf2f(v.y >> 16);
    f[4] = bf2f(v.z & 0xffffu); f[5] = bf2f(v.z >> 16);
    f[6] = bf2f(v.w & 0xffffu); f[7] = bf2f(v.w >> 16);
}

// ---------------- launch A: edge count/rank + all-W transpose ----------------
__global__ __launch_bounds__(256) void k_count_prep(const int* __restrict__ dst, int* __restrict__ deg,
                                                    int* __restrict__ rank, int E, int nbE,
                                                    const float* __restrict__ W1, const float* __restrict__ W2,
                                                    const float* __restrict__ W3, unsigned short* __restrict__ Wt1,
                                                    unsigned short* __restrict__ Wt2, unsigned short* __restrict__ Wt3) {
    if ((int)blockIdx.x < nbE) {
        int e = blockIdx.x * 256 + threadIdx.x;
        if (e < E) rank[e] = atomicAdd(&deg[dst[e]], 1);
    } else {
        int t = (blockIdx.x - nbE) * 256 + threadIdx.x;
        if (t < 16384) {
            int k = t & 127, n = t >> 7;
            Wt1[n * 128 + k] = (unsigned short)f2bf1(W1[(size_t)k * 128 + n]);
        } else if (t < 32768) {
            int u = t - 16384;
            int k = u & 127, n = u >> 7;
            Wt2[n * 128 + k] = (unsigned short)f2bf1(W2[(size_t)k * 128 + n]);
        } else if (t < 40960) {
            int u = t - 32768;
            int k = u & 127, n = u >> 7;
            Wt3[n * 128 + k] = (unsigned short)f2bf1(W3[(size_t)k * 64 + n]);
        }
    }
}

// ---------------- launch B: deg block-reduce + layer-1 MFMA GEMM (R9 structure) ----------------
__global__ __launch_bounds__(256) void k_reduce_gemm1(const int* __restrict__ deg, int* __restrict__ bsum, int n, int nb,
                                                      const float* __restrict__ X, const unsigned short* __restrict__ Wt,
                                                      unsigned short* __restrict__ O, int nrows) {
    constexpr int LDR = 136;
    __shared__ __align__(16) unsigned char smem[(64 * LDR + 128 * LDR) * 2];  // 52224 B

    const int tid = threadIdx.x;
    if ((int)blockIdx.x < nb) {
        int* s = (int*)smem;
        int i = blockIdx.x * 256 + tid;
        s[tid] = (i < n) ? deg[i] : 0;
        __syncthreads();
        for (int off = 128; off > 0; off >>= 1) {
            if (tid < off) s[tid] += s[tid + off];
            __syncthreads();
        }
        if (tid == 0) bsum[blockIdx.x] = s[0];
        return;
    }

    unsigned short* sX = (unsigned short*)smem;
    unsigned short* sB = sX + 64 * LDR;
    const int row0 = ((int)blockIdx.x - nb) * 64;

#pragma unroll
    for (int i = 0; i < 4; ++i) {
        int idx = tid + i * 256;
        int r = idx >> 4, c8 = idx & 15;
        int grow = row0 + r;
        uint4 v = make_uint4(0, 0, 0, 0);
        if (grow < nrows) {
            float4 a = ld4(X + (size_t)grow * 128 + c8 * 8);
            float4 b = ld4(X + (size_t)grow * 128 + c8 * 8 + 4);
            v = make_uint4(f2bf2(a.x, a.y), f2bf2(a.z, a.w), f2bf2(b.x, b.y), f2bf2(b.z, b.w));
        }
        *reinterpret_cast<uint4*>(&sX[r * LDR + c8 * 8]) = v;
    }
#pragma unroll
    for (int i = 0; i < 8; ++i) {
        int idx = tid + i * 256;
        int nn = idx >> 4, c8 = idx & 15;
        *reinterpret_cast<uint4*>(&sB[nn * LDR + c8 * 8]) =
            *reinterpret_cast<const uint4*>(Wt + (size_t)nn * 128 + c8 * 8);
    }
    __syncthreads();

    const int lane = tid & 63;
    const int wave = tid >> 6;
    const int l15  = lane & 15;
    const int quad = lane >> 4;

    floatx4 acc[8];
#pragma unroll
    for (int j = 0; j < 8; ++j) acc[j] = (floatx4){0.f, 0.f, 0.f, 0.f};

    const unsigned short* xbase = &sX[(wave * 16 + l15) * LDR + quad * 8];
#pragma unroll
    for (int kk = 0; kk < 4; ++kk) {
        short8 xb = *reinterpret_cast<const short8*>(xbase + kk * 32);
#pragma unroll
        for (int j = 0; j < 8; ++j) {
            short8 wa = *reinterpret_cast<const short8*>(&sB[(j * 16 + l15) * LDR + quad * 8 + kk * 32]);
            acc[j] = __builtin_amdgcn_mfma_f32_16x16x32_bf16(wa, xb, acc[j], 0, 0, 0);
        }
    }

    int xrow = row0 + wave * 16 + l15;
    if (xrow < nrows) {
#pragma unroll
        for (int j = 0; j < 8; ++j) {
            uint2 o = make_uint2(f2bf2(acc[j][0], acc[j][1]), f2bf2(acc[j][2], acc[j][3]));
            *reinterpret_cast<uint2*>(O + (size_t)xrow * 128 + j * 16 + quad * 4) = o;
        }
    }
}

// ---------------- scan kernels (R9 parallel structure) ----------------
__global__ __launch_bounds__(256) void k_scan_small(const int* __restrict__ bsum, int* __restrict__ boff, int nb) {
    __shared__ int s[256];
    int t = threadIdx.x;
    int v = (t < nb) ? bsum[t] : 0;
    s[t] = v;
    __syncthreads();
    for (int off = 1; off < 256; off <<= 1) {
        int x = (t >= off) ? s[t - off] : 0;
        __syncthreads();
        s[t] += x;
        __syncthreads();
    }
    if (t < nb) boff[t] = s[t] - v;  // exclusive
}

__global__ __launch_bounds__(256) void k_scan_final(const int* __restrict__ deg, const int* __restrict__ boff,
                                                    int* __restrict__ row_off, float* __restrict__ dinv, int n) {
    __shared__ int s[256];
    int t = threadIdx.x;
    int i = blockIdx.x * 256 + t;
    int v = (i < n) ? deg[i] : 0;
    s[t] = v;
    __syncthreads();
    for (int off = 1; off < 256; off <<= 1) {
        int x = (t >= off) ? s[t - off] : 0;
        __syncthreads();
        s[t] += x;
        __syncthreads();
    }
    int incl = s[t] + boff[blockIdx.x];
    if (i < n) {
        row_off[i] = incl - v;
        dinv[i]    = 1.0f / sqrtf((float)v + 1.0f);
        if (i == n - 1) row_off[n] = incl;
    }
}

// ---------------- launch C: CSR fill (4B scatter) + bufA *= dinv[row] scale ----------------
__global__ __launch_bounds__(256) void k_fill_scale(const int* __restrict__ src, const int* __restrict__ dst,
                                                    const int* __restrict__ rank, const int* __restrict__ roff,
                                                    int* __restrict__ csrc, int E, int nbE,
                                                    unsigned short* __restrict__ A, const float* __restrict__ dinv,
                                                    int n16) {
    if ((int)blockIdx.x < nbE) {
        int e = blockIdx.x * 256 + threadIdx.x;
        if (e < E) csrc[roff[dst[e]] + rank[e]] = src[e];
    } else {
        int idx = (blockIdx.x - nbE) * 256 + threadIdx.x;
        if (idx < n16) {
            float di = dinv[idx >> 4];
            uint4 v = *reinterpret_cast<const uint4*>(A + (size_t)idx * 8);
            float f[8];
            unpack8(v, f);
#pragma unroll
            for (int i = 0; i < 8; ++i) f[i] *= di;
            uint4 o = make_uint4(f2bf2(f[0], f[1]), f2bf2(f[2], f[3]), f2bf2(f[4], f[5]), f2bf2(f[6], f[7]));
            *reinterpret_cast<uint4*>(A + (size_t)idx * 8) = o;
        }
    }
}

// ---------------- MFMA GEMM (layers 2/3): O = (X @ W) * dinv[row], bf16 ----------------
template <int NC>
__global__ __launch_bounds__(256) void k_gemm_mfma(const unsigned short* __restrict__ X,
                                                   const unsigned short* __restrict__ Wt,
                                                   const float* __restrict__ dinv,
                                                   unsigned short* __restrict__ O, int nrows) {
    constexpr int LDR = 136;
    __shared__ unsigned short sX[64 * LDR];
    __shared__ unsigned short sB[NC * LDR];

    const int tid  = threadIdx.x;
    const int row0 = blockIdx.x * 64;

#pragma unroll
    for (int i = 0; i < 4; ++i) {
        int idx = tid + i * 256;
        int r = idx >> 4, c8 = idx & 15;
        int grow = row0 + r;
        uint4 v = make_uint4(0, 0, 0, 0);
        if (grow < nrows) v = *reinterpret_cast<const uint4*>(X + (size_t)grow * 128 + c8 * 8);
        *reinterpret_cast<uint4*>(&sX[r * LDR + c8 * 8]) = v;
    }
#pragma unroll
    for (int i = 0; i < NC / 16; ++i) {
        int idx = tid + i * 256;
        int n = idx >> 4, c8 = idx & 15;
        *reinterpret_cast<uint4*>(&sB[n * LDR + c8 * 8]) =
            *reinterpret_cast<const uint4*>(Wt + (size_t)n * 128 + c8 * 8);
    }
    __syncthreads();

    const int lane = tid & 63;
    const int wave = tid >> 6;
    const int l15  = lane & 15;
    const int quad = lane >> 4;

    floatx4 acc[NC / 16];
#pragma unroll
    for (int j = 0; j < NC / 16; ++j) acc[j] = (floatx4){0.f, 0.f, 0.f, 0.f};

    const unsigned short* xbase = &sX[(wave * 16 + l15) * LDR + quad * 8];
#pragma unroll
    for (int kk = 0; kk < 4; ++kk) {
        short8 xb = *reinterpret_cast<const short8*>(xbase + kk * 32);
#pragma unroll
        for (int j = 0; j < NC / 16; ++j) {
            short8 wa = *reinterpret_cast<const short8*>(&sB[(j * 16 + l15) * LDR + quad * 8 + kk * 32]);
            acc[j] = __builtin_amdgcn_mfma_f32_16x16x32_bf16(wa, xb, acc[j], 0, 0, 0);
        }
    }

    int xrow = row0 + wave * 16 + l15;
    if (xrow < nrows) {
        float di = dinv[xrow];
#pragma unroll
        for (int j = 0; j < NC / 16; ++j) {
            uint2 o = make_uint2(f2bf2(acc[j][0] * di, acc[j][1] * di), f2bf2(acc[j][2] * di, acc[j][3] * di));
            *reinterpret_cast<uint2*>(O + (size_t)xrow * NC + j * 16 + quad * 4) = o;
        }
    }
}

// ---------------- aggregation (128 feats, pre-scaled bf16 H') + bias + relu ----------------
// 16 lanes/node, 8 feats/lane; 4-deep gather batches with csrc software prefetch.
__global__ __launch_bounds__(256) void k_agg_relu(const unsigned short* __restrict__ H, const int* __restrict__ roff,
                                                  const int* __restrict__ csrc, const float* __restrict__ dinv,
                                                  const float* __restrict__ bias, unsigned short* __restrict__ O, int n) {
    int t    = blockIdx.x * 256 + threadIdx.x;
    int node = t >> 4;
    int f8   = (t & 15) * 8;
    if (node >= n) return;

    float a[8];
    {
        uint4 hv = *reinterpret_cast<const uint4*>(H + (size_t)node * 128 + f8);
        unpack8(hv, a);  // self term H'[node]
    }

    int e  = roff[node];
    int e1 = roff[node + 1];
    int nfull = (e1 - e) >> 2;

    if (nfull > 0) {
        int s[4];
#pragma unroll
        for (int u = 0; u < 4; ++u) s[u] = csrc[e + u];
        for (int b = 1; b < nfull; ++b) {
            uint4 v[4];
#pragma unroll
            for (int u = 0; u < 4; ++u) v[u] = *reinterpret_cast<const uint4*>(H + (size_t)s[u] * 128 + f8);
            int sn[4];
            int base = e + b * 4;
#pragma unroll
            for (int u = 0; u < 4; ++u) sn[u] = csrc[base + u];  // prefetch next batch
#pragma unroll
            for (int u = 0; u < 4; ++u) {
                float g[8];
                unpack8(v[u], g);
#pragma unroll
                for (int i = 0; i < 8; ++i) a[i] += g[i];
            }
#pragma unroll
            for (int u = 0; u < 4; ++u) s[u] = sn[u];
        }
        uint4 v[4];
#pragma unroll
        for (int u = 0; u < 4; ++u) v[u] = *reinterpret_cast<const uint4*>(H + (size_t)s[u] * 128 + f8);
#pragma unroll
        for (int u = 0; u < 4; ++u) {
            float g[8];
            unpack8(v[u], g);
#pragma unroll
            for (int i = 0; i < 8; ++i) a[i] += g[i];
        }
        e += nfull * 4;
    }
    for (; e < e1; ++e) {
        uint4 v0 = *reinterpret_cast<const uint4*>(H + (size_t)csrc[e] * 128 + f8);
        float g0[8];
        unpack8(v0, g0);
#pragma unroll
        for (int i = 0; i < 8; ++i) a[i] += g0[i];
    }

    float di = dinv[node];
    float4 b0 = ld4(bias + f8);
    float4 b1 = ld4(bias + f8 + 4);
    float bb[8] = {b0.x, b0.y, b0.z, b0.w, b1.x, b1.y, b1.z, b1.w};
#pragma unroll
    for (int i = 0; i < 8; ++i) a[i] = fmaxf(a[i] * di + bb[i], 0.0f);

    uint4 ov = make_uint4(f2bf2(a[0], a[1]), f2bf2(a[2], a[3]), f2bf2(a[4], a[5]), f2bf2(a[6], a[7]));
    *reinterpret_cast<uint4*>(O + (size_t)node * 128 + f8) = ov;
}

// ---------------- aggregation (64 feats, pre-scaled bf16 H') + bias + log_softmax ----------------
// 8 lanes/node, 8 feats/lane; 8-deep batches with csrc software prefetch.
__global__ __launch_bounds__(256) void k_agg_softmax(const unsigned short* __restrict__ H, const int* __restrict__ roff,
                                                     const int* __restrict__ csrc, const float* __restrict__ dinv,
                                                     const float* __restrict__ bias, float* __restrict__ O, int n) {
    int t    = blockIdx.x * 256 + threadIdx.x;
    int node = t >> 3;
    int f8   = (t & 7) * 8;
    if (node >= n) return;

    float a[8];
    {
        uint4 hv = *reinterpret_cast<const uint4*>(H + (size_t)node * 64 + f8);
        unpack8(hv, a);  // self term
    }

    int e  = roff[node];
    int e1 = roff[node + 1];
    int nfull = (e1 - e) >> 3;

    if (nfull > 0) {
        int s[8];
#pragma unroll
        for (int u = 0; u < 8; ++u) s[u] = csrc[e + u];
        for (int b = 1; b < nfull; ++b) {
            uint4 v[8];
#pragma unroll
            for (int u = 0; u < 8; ++u) v[u] = *reinterpret_cast<const uint4*>(H + (size_t)s[u] * 64 + f8);
            int sn[8];
            int base = e + b * 8;
#pragma unroll
            for (int u = 0; u < 8; ++u) sn[u] = csrc[base + u];
#pragma unroll
            for (int u = 0; u < 8; ++u) {
                float gg[8];
                unpack8(v[u], gg);
#pragma unroll
                for (int i = 0; i < 8; ++i) a[i] += gg[i];
            }
#pragma unroll
            for (int u = 0; u < 8; ++u) s[u] = sn[u];
        }
        uint4 v[8];
#pragma unroll
        for (int u = 0; u < 8; ++u) v[u] = *reinterpret_cast<const uint4*>(H + (size_t)s[u] * 64 + f8);
#pragma unroll
        for (int u = 0; u < 8; ++u) {
            float gg[8];
            unpack8(v[u], gg);
#pragma unroll
            for (int i = 0; i < 8; ++i) a[i] += gg[i];
        }
        e += nfull * 8;
    }
    for (; e < e1; ++e) {
        uint4 v0 = *reinterpret_cast<const uint4*>(H + (size_t)csrc[e] * 64 + f8);
        float g0[8];
        unpack8(v0, g0);
#pragma unroll
        for (int i = 0; i < 8; ++i) a[i] += g0[i];
    }

    float di = dinv[node];
    float4 b0 = ld4(bias + f8);
    float4 b1 = ld4(bias + f8 + 4);
    float bb[8] = {b0.x, b0.y, b0.z, b0.w, b1.x, b1.y, b1.z, b1.w};
    float v[8];
#pragma unroll
    for (int i = 0; i < 8; ++i) v[i] = a[i] * di + bb[i];

    float m = v[0];
#pragma unroll
    for (int i = 1; i < 8; ++i) m = fmaxf(m, v[i]);
    m = fmaxf(m, __shfl_xor(m, 1));
    m = fmaxf(m, __shfl_xor(m, 2));
    m = fmaxf(m, __shfl_xor(m, 4));

    float ssum = 0.0f;
#pragma unroll
    for (int i = 0; i < 8; ++i) ssum += expf(v[i] - m);
    ssum += __shfl_xor(ssum, 1);
    ssum += __shfl_xor(ssum, 2);
    ssum += __shfl_xor(ssum, 4);
    float ls = logf(ssum);

    float* op = O + (size_t)node * 64 + f8;
    st4(op, make_float4(v[0] - m - ls, v[1] - m - ls, v[2] - m - ls, v[3] - m - ls));
    st4(op + 4, make_float4(v[4] - m - ls, v[5] - m - ls, v[6] - m - ls, v[7] - m - ls));
}

// ---------------- launch ----------------
extern "C" void kernel_launch(void* const* d_in, const int* in_sizes, int n_in,
                              void* d_out, int out_size, void* d_ws, size_t ws_size,
                              hipStream_t stream) {
    const float* x  = (const float*)d_in[0];
    const int*   ei = (const int*)d_in[1];
    const float* W1 = (const float*)d_in[2];
    const float* b1 = (const float*)d_in[3];
    const float* W2 = (const float*)d_in[4];
    const float* b2 = (const float*)d_in[5];
    const float* W3 = (const float*)d_in[6];
    const float* b3 = (const float*)d_in[7];
    float* out = (float*)d_out;

    const int N = in_sizes[0] / 128;
    const int E = in_sizes[1] / 2;
    const int* src = ei;
    const int* dst = ei + E;

    char* ws = (char*)d_ws;
    size_t off = 0;
    auto alloc = [&](size_t bytes) -> char* {
        char* p = ws + off;
        off = (off + bytes + 255) & ~(size_t)255;
        return p;
    };
    int nb  = (N + 255) / 256;
    int nbE = (E + 255) / 256;
    int blocks64 = (N + 63) / 64;
    int n16 = N * 16;
    int nbS = (n16 + 255) / 256;

    int*   deg     = (int*)alloc((size_t)N * 4);
    int*   row_off = (int*)alloc(((size_t)N + 1) * 4);
    float* dinv    = (float*)alloc((size_t)N * 4);
    int*   bsum    = (int*)alloc((size_t)nb * 4);
    int*   boff    = (int*)alloc((size_t)nb * 4);
    int*   rank    = (int*)alloc((size_t)E * 4);
    int*   csrc    = (int*)alloc((size_t)E * 4);
    unsigned short* Wt1  = (unsigned short*)alloc(128 * 128 * 2);
    unsigned short* Wt2  = (unsigned short*)alloc(128 * 128 * 2);
    unsigned short* Wt3  = (unsigned short*)alloc(64 * 128 * 2);
    unsigned short* bufA = (unsigned short*)alloc((size_t)N * 128 * 2);
    unsigned short* bufB = (unsigned short*)alloc((size_t)N * 128 * 2);
    unsigned short* bufC = (unsigned short*)alloc((size_t)N * 64 * 2);
    (void)ws_size; (void)n_in; (void)out_size;

    hipMemsetAsync(deg, 0, (size_t)N * 4, stream);
    // A: edge count/rank + W transposes (independent)
    k_count_prep<<<nbE + 160, 256, 0, stream>>>(dst, deg, rank, E, nbE, W1, W2, W3, Wt1, Wt2, Wt3);
    // B: deg reduce + layer-1 GEMM (unscaled)
    k_reduce_gemm1<<<nb + blocks64, 256, 0, stream>>>(deg, bsum, N, nb, x, Wt1, bufA, N);
    k_scan_small<<<1, 256, 0, stream>>>(bsum, boff, nb);
    k_scan_final<<<nb, 256, 0, stream>>>(deg, boff, row_off, dinv, N);
    // C: CSR fill (4B) + bufA *= dinv
    k_fill_scale<<<nbE + nbS, 256, 0, stream>>>(src, dst, rank, row_off, csrc, E, nbE, bufA, dinv, n16);

    // layer 1 aggregation (pre-scaled bufA)
    k_agg_relu<<<((size_t)N * 16 + 255) / 256, 256, 0, stream>>>(bufA, row_off, csrc, dinv, b1, bufB, N);
    // layer 2 (epilogue scales by dinv)
    k_gemm_mfma<128><<<blocks64, 256, 0, stream>>>(bufB, Wt2, dinv, bufA, N);
    k_agg_relu<<<((size_t)N * 16 + 255) / 256, 256, 0, stream>>>(bufA, row_off, csrc, dinv, b2, bufB, N);
    // layer 3 + log_softmax
    k_gemm_mfma<64><<<blocks64, 256, 0, stream>>>(bufB, Wt3, dinv, bufC, N);
    k_agg_softmax<<<((size_t)N * 8 + 255) / 256, 256, 0, stream>>>(bufC, row_off, csrc, dinv, b3, out, N);
}

// Round 12
// 252.184 us; speedup vs baseline: 1.4254x; 1.0101x over previous
//
#include <hip/hip_runtime.h>
#include <math.h>

// ---------------- helpers ----------------
typedef short short8 __attribute__((ext_vector_type(8)));
typedef float floatx4 __attribute__((ext_vector_type(4)));

__device__ __forceinline__ float4 ld4(const float* p) { return *reinterpret_cast<const float4*>(p); }
__device__ __forceinline__ void st4(float* p, float4 v) { *reinterpret_cast<float4*>(p) = v; }

__device__ __forceinline__ float bf2f(unsigned int u) { return __uint_as_float(u << 16); }
__device__ __forceinline__ unsigned int f2bf1(float f) {
    unsigned int x = __float_as_uint(f);
    return (x + 0x7fffu + ((x >> 16) & 1u)) >> 16;  // RNE
}
__device__ __forceinline__ unsigned int f2bf2(float lo, float hi) {
    return f2bf1(lo) | (f2bf1(hi) << 16);
}
__device__ __forceinline__ void unpack8(uint4 v, float* f) {
    f[0] = bf2f(v.x & 0xffffu); f[1] = bf2f(v.x >> 16);
    f[2] = bf2f(v.y & 0xffffu); f[3] = bf2f(v.y >> 16);
    f[4] = bf2f(v.z & 0xffffu); f[5] = bf2f(v.z >> 16);
    f[6] = bf2f(v.w & 0xffffu); f[7] = bf2f(v.w >> 16);
}

// ---------------- launch A: edge count/rank + all-W transpose ----------------
__global__ __launch_bounds__(256) void k_count_prep(const int* __restrict__ dst, int* __restrict__ deg,
                                                    int* __restrict__ rank, int E, int nbE,
                                                    const float* __restrict__ W1, const float* __restrict__ W2,
                                                    const float* __restrict__ W3, unsigned short* __restrict__ Wt1,
                                                    unsigned short* __restrict__ Wt2, unsigned short* __restrict__ Wt3) {
    if ((int)blockIdx.x < nbE) {
        int e = blockIdx.x * 256 + threadIdx.x;
        if (e < E) rank[e] = atomicAdd(&deg[dst[e]], 1);
    } else {
        int t = (blockIdx.x - nbE) * 256 + threadIdx.x;
        if (t < 16384) {
            int k = t & 127, n = t >> 7;
            Wt1[n * 128 + k] = (unsigned short)f2bf1(W1[(size_t)k * 128 + n]);
        } else if (t < 32768) {
            int u = t - 16384;
            int k = u & 127, n = u >> 7;
            Wt2[n * 128 + k] = (unsigned short)f2bf1(W2[(size_t)k * 128 + n]);
        } else if (t < 40960) {
            int u = t - 32768;
            int k = u & 127, n = u >> 7;
            Wt3[n * 128 + k] = (unsigned short)f2bf1(W3[(size_t)k * 64 + n]);
        }
    }
}

// ---------------- launch B: dinv (blocks [0,nbN)) + deg block-reduce (blocks [nbN, nbN+nb)) ----------------
__global__ __launch_bounds__(256) void k_dinv_reduce(const int* __restrict__ deg, float* __restrict__ dinv,
                                                     int* __restrict__ bsum, int n, int nbN) {
    __shared__ int s[256];
    int t = threadIdx.x;
    if ((int)blockIdx.x < nbN) {
        int i = blockIdx.x * 256 + t;
        if (i < n) dinv[i] = 1.0f / sqrtf((float)deg[i] + 1.0f);
        return;
    }
    int b = (int)blockIdx.x - nbN;
    int i = b * 256 + t;
    s[t] = (i < n) ? deg[i] : 0;
    __syncthreads();
    for (int off = 128; off > 0; off >>= 1) {
        if (t < off) s[t] += s[t + off];
        __syncthreads();
    }
    if (t == 0) bsum[b] = s[0];
}

// ---------------- launch C: scan_small (block 0) + layer-1 MFMA GEMM with dinv pre-scale ----------------
__global__ __launch_bounds__(256) void k_scansmall_gemm1(const int* __restrict__ bsum, int* __restrict__ boff, int nb,
                                                         const float* __restrict__ X, const unsigned short* __restrict__ Wt,
                                                         const float* __restrict__ dinv,
                                                         unsigned short* __restrict__ O, int nrows) {
    constexpr int LDR = 136;
    __shared__ __align__(16) unsigned char smem[(64 * LDR + 128 * LDR) * 2];  // 52224 B

    const int tid = threadIdx.x;
    if (blockIdx.x == 0) {
        int* s = (int*)smem;
        int v = (tid < nb) ? bsum[tid] : 0;
        s[tid] = v;
        __syncthreads();
        for (int off = 1; off < 256; off <<= 1) {
            int x = (tid >= off) ? s[tid - off] : 0;
            __syncthreads();
            s[tid] += x;
            __syncthreads();
        }
        if (tid < nb) boff[tid] = s[tid] - v;  // exclusive
        return;
    }

    unsigned short* sX = (unsigned short*)smem;
    unsigned short* sB = sX + 64 * LDR;
    const int row0 = ((int)blockIdx.x - 1) * 64;

#pragma unroll
    for (int i = 0; i < 4; ++i) {
        int idx = tid + i * 256;
        int r = idx >> 4, c8 = idx & 15;
        int grow = row0 + r;
        uint4 v = make_uint4(0, 0, 0, 0);
        if (grow < nrows) {
            float4 a = ld4(X + (size_t)grow * 128 + c8 * 8);
            float4 b = ld4(X + (size_t)grow * 128 + c8 * 8 + 4);
            v = make_uint4(f2bf2(a.x, a.y), f2bf2(a.z, a.w), f2bf2(b.x, b.y), f2bf2(b.z, b.w));
        }
        *reinterpret_cast<uint4*>(&sX[r * LDR + c8 * 8]) = v;
    }
#pragma unroll
    for (int i = 0; i < 8; ++i) {
        int idx = tid + i * 256;
        int nn = idx >> 4, c8 = idx & 15;
        *reinterpret_cast<uint4*>(&sB[nn * LDR + c8 * 8]) =
            *reinterpret_cast<const uint4*>(Wt + (size_t)nn * 128 + c8 * 8);
    }
    __syncthreads();

    const int lane = tid & 63;
    const int wave = tid >> 6;
    const int l15  = lane & 15;
    const int quad = lane >> 4;

    floatx4 acc[8];
#pragma unroll
    for (int j = 0; j < 8; ++j) acc[j] = (floatx4){0.f, 0.f, 0.f, 0.f};

    const unsigned short* xbase = &sX[(wave * 16 + l15) * LDR + quad * 8];
#pragma unroll
    for (int kk = 0; kk < 4; ++kk) {
        short8 xb = *reinterpret_cast<const short8*>(xbase + kk * 32);
#pragma unroll
        for (int j = 0; j < 8; ++j) {
            short8 wa = *reinterpret_cast<const short8*>(&sB[(j * 16 + l15) * LDR + quad * 8 + kk * 32]);
            acc[j] = __builtin_amdgcn_mfma_f32_16x16x32_bf16(wa, xb, acc[j], 0, 0, 0);
        }
    }

    int xrow = row0 + wave * 16 + l15;
    if (xrow < nrows) {
        float di = dinv[xrow];
#pragma unroll
        for (int j = 0; j < 8; ++j) {
            uint2 o = make_uint2(f2bf2(acc[j][0] * di, acc[j][1] * di), f2bf2(acc[j][2] * di, acc[j][3] * di));
            *reinterpret_cast<uint2*>(O + (size_t)xrow * 128 + j * 16 + quad * 4) = o;
        }
    }
}

// ---------------- launch D: final scan -> row_off ----------------
__global__ __launch_bounds__(256) void k_scan_final(const int* __restrict__ deg, const int* __restrict__ boff,
                                                    int* __restrict__ row_off, int n) {
    __shared__ int s[256];
    int t = threadIdx.x;
    int i = blockIdx.x * 256 + t;
    int v = (i < n) ? deg[i] : 0;
    s[t] = v;
    __syncthreads();
    for (int off = 1; off < 256; off <<= 1) {
        int x = (t >= off) ? s[t - off] : 0;
        __syncthreads();
        s[t] += x;
        __syncthreads();
    }
    int incl = s[t] + boff[blockIdx.x];
    if (i < n) {
        row_off[i] = incl - v;
        if (i == n - 1) row_off[n] = incl;
    }
}

// ---------------- launch E: CSR fill (4B scatter only) ----------------
__global__ __launch_bounds__(256) void k_fill(const int* __restrict__ src, const int* __restrict__ dst,
                                              const int* __restrict__ rank, const int* __restrict__ roff,
                                              int* __restrict__ csrc, int E) {
    int e = blockIdx.x * 256 + threadIdx.x;
    if (e < E) csrc[roff[dst[e]] + rank[e]] = src[e];
}

// ---------------- MFMA GEMM (layers 2/3): O = (X @ W) * dinv[row], bf16 ----------------
template <int NC>
__global__ __launch_bounds__(256) void k_gemm_mfma(const unsigned short* __restrict__ X,
                                                   const unsigned short* __restrict__ Wt,
                                                   const float* __restrict__ dinv,
                                                   unsigned short* __restrict__ O, int nrows) {
    constexpr int LDR = 136;
    __shared__ unsigned short sX[64 * LDR];
    __shared__ unsigned short sB[NC * LDR];

    const int tid  = threadIdx.x;
    const int row0 = blockIdx.x * 64;

#pragma unroll
    for (int i = 0; i < 4; ++i) {
        int idx = tid + i * 256;
        int r = idx >> 4, c8 = idx & 15;
        int grow = row0 + r;
        uint4 v = make_uint4(0, 0, 0, 0);
        if (grow < nrows) v = *reinterpret_cast<const uint4*>(X + (size_t)grow * 128 + c8 * 8);
        *reinterpret_cast<uint4*>(&sX[r * LDR + c8 * 8]) = v;
    }
#pragma unroll
    for (int i = 0; i < NC / 16; ++i) {
        int idx = tid + i * 256;
        int n = idx >> 4, c8 = idx & 15;
        *reinterpret_cast<uint4*>(&sB[n * LDR + c8 * 8]) =
            *reinterpret_cast<const uint4*>(Wt + (size_t)n * 128 + c8 * 8);
    }
    __syncthreads();

    const int lane = tid & 63;
    const int wave = tid >> 6;
    const int l15  = lane & 15;
    const int quad = lane >> 4;

    floatx4 acc[NC / 16];
#pragma unroll
    for (int j = 0; j < NC / 16; ++j) acc[j] = (floatx4){0.f, 0.f, 0.f, 0.f};

    const unsigned short* xbase = &sX[(wave * 16 + l15) * LDR + quad * 8];
#pragma unroll
    for (int kk = 0; kk < 4; ++kk) {
        short8 xb = *reinterpret_cast<const short8*>(xbase + kk * 32);
#pragma unroll
        for (int j = 0; j < NC / 16; ++j) {
            short8 wa = *reinterpret_cast<const short8*>(&sB[(j * 16 + l15) * LDR + quad * 8 + kk * 32]);
            acc[j] = __builtin_amdgcn_mfma_f32_16x16x32_bf16(wa, xb, acc[j], 0, 0, 0);
        }
    }

    int xrow = row0 + wave * 16 + l15;
    if (xrow < nrows) {
        float di = dinv[xrow];
#pragma unroll
        for (int j = 0; j < NC / 16; ++j) {
            uint2 o = make_uint2(f2bf2(acc[j][0] * di, acc[j][1] * di), f2bf2(acc[j][2] * di, acc[j][3] * di));
            *reinterpret_cast<uint2*>(O + (size_t)xrow * NC + j * 16 + quad * 4) = o;
        }
    }
}

// ---------------- aggregation (128 feats, pre-scaled bf16 H') + bias + relu ----------------
// 16 lanes/node, 8 feats/lane, 4-deep gather batches (R9 best-measured body).
__global__ __launch_bounds__(256) void k_agg_relu(const unsigned short* __restrict__ H, const int* __restrict__ roff,
                                                  const int* __restrict__ csrc, const float* __restrict__ dinv,
                                                  const float* __restrict__ bias, unsigned short* __restrict__ O, int n) {
    int t    = blockIdx.x * 256 + threadIdx.x;
    int node = t >> 4;
    int f8   = (t & 15) * 8;
    if (node >= n) return;

    float a[8];
    {
        uint4 hv = *reinterpret_cast<const uint4*>(H + (size_t)node * 128 + f8);
        unpack8(hv, a);  // self term H'[node]
    }

    int e  = roff[node];
    int e1 = roff[node + 1];
    for (; e + 3 < e1; e += 4) {
        int s[4];
        uint4 v[4];
#pragma unroll
        for (int u = 0; u < 4; ++u) s[u] = csrc[e + u];
#pragma unroll
        for (int u = 0; u < 4; ++u) v[u] = *reinterpret_cast<const uint4*>(H + (size_t)s[u] * 128 + f8);
#pragma unroll
        for (int u = 0; u < 4; ++u) {
            float g[8];
            unpack8(v[u], g);
#pragma unroll
            for (int i = 0; i < 8; ++i) a[i] += g[i];
        }
    }
    for (; e < e1; ++e) {
        uint4 v0 = *reinterpret_cast<const uint4*>(H + (size_t)csrc[e] * 128 + f8);
        float g0[8];
        unpack8(v0, g0);
#pragma unroll
        for (int i = 0; i < 8; ++i) a[i] += g0[i];
    }

    float di = dinv[node];
    float4 b0 = ld4(bias + f8);
    float4 b1 = ld4(bias + f8 + 4);
    float bb[8] = {b0.x, b0.y, b0.z, b0.w, b1.x, b1.y, b1.z, b1.w};
#pragma unroll
    for (int i = 0; i < 8; ++i) a[i] = fmaxf(a[i] * di + bb[i], 0.0f);

    uint4 ov = make_uint4(f2bf2(a[0], a[1]), f2bf2(a[2], a[3]), f2bf2(a[4], a[5]), f2bf2(a[6], a[7]));
    *reinterpret_cast<uint4*>(O + (size_t)node * 128 + f8) = ov;
}

// ---------------- aggregation (64 feats, pre-scaled bf16 H') + bias + log_softmax ----------------
// 8 lanes/node, 8 feats/lane, 8-deep batches (R9 body).
__global__ __launch_bounds__(256) void k_agg_softmax(const unsigned short* __restrict__ H, const int* __restrict__ roff,
                                                     const int* __restrict__ csrc, const float* __restrict__ dinv,
                                                     const float* __restrict__ bias, float* __restrict__ O, int n) {
    int t    = blockIdx.x * 256 + threadIdx.x;
    int node = t >> 3;
    int f8   = (t & 7) * 8;
    if (node >= n) return;

    float a[8];
    {
        uint4 hv = *reinterpret_cast<const uint4*>(H + (size_t)node * 64 + f8);
        unpack8(hv, a);  // self term
    }

    int e  = roff[node];
    int e1 = roff[node + 1];
    for (; e + 7 < e1; e += 8) {
        int s[8];
        uint4 v[8];
#pragma unroll
        for (int u = 0; u < 8; ++u) s[u] = csrc[e + u];
#pragma unroll
        for (int u = 0; u < 8; ++u) v[u] = *reinterpret_cast<const uint4*>(H + (size_t)s[u] * 64 + f8);
#pragma unroll
        for (int u = 0; u < 8; ++u) {
            float gg[8];
            unpack8(v[u], gg);
#pragma unroll
            for (int i = 0; i < 8; ++i) a[i] += gg[i];
        }
    }
    if (e + 3 < e1) {
        int s[4];
        uint4 v[4];
#pragma unroll
        for (int u = 0; u < 4; ++u) s[u] = csrc[e + u];
#pragma unroll
        for (int u = 0; u < 4; ++u) v[u] = *reinterpret_cast<const uint4*>(H + (size_t)s[u] * 64 + f8);
#pragma unroll
        for (int u = 0; u < 4; ++u) {
            float gg[8];
            unpack8(v[u], gg);
#pragma unroll
            for (int i = 0; i < 8; ++i) a[i] += gg[i];
        }
        e += 4;
    }
    for (; e < e1; ++e) {
        uint4 v0 = *reinterpret_cast<const uint4*>(H + (size_t)csrc[e] * 64 + f8);
        float g0[8];
        unpack8(v0, g0);
#pragma unroll
        for (int i = 0; i < 8; ++i) a[i] += g0[i];
    }

    float di = dinv[node];
    float4 b0 = ld4(bias + f8);
    float4 b1 = ld4(bias + f8 + 4);
    float bb[8] = {b0.x, b0.y, b0.z, b0.w, b1.x, b1.y, b1.z, b1.w};
    float v[8];
#pragma unroll
    for (int i = 0; i < 8; ++i) v[i] = a[i] * di + bb[i];

    float m = v[0];
#pragma unroll
    for (int i = 1; i < 8; ++i) m = fmaxf(m, v[i]);
    m = fmaxf(m, __shfl_xor(m, 1));
    m = fmaxf(m, __shfl_xor(m, 2));
    m = fmaxf(m, __shfl_xor(m, 4));

    float ssum = 0.0f;
#pragma unroll
    for (int i = 0; i < 8; ++i) ssum += expf(v[i] - m);
    ssum += __shfl_xor(ssum, 1);
    ssum += __shfl_xor(ssum, 2);
    ssum += __shfl_xor(ssum, 4);
    float ls = logf(ssum);

    float* op = O + (size_t)node * 64 + f8;
    st4(op, make_float4(v[0] - m - ls, v[1] - m - ls, v[2] - m - ls, v[3] - m - ls));
    st4(op + 4, make_float4(v[4] - m - ls, v[5] - m - ls, v[6] - m - ls, v[7] - m - ls));
}

// ---------------- launch ----------------
extern "C" void kernel_launch(void* const* d_in, const int* in_sizes, int n_in,
                              void* d_out, int out_size, void* d_ws, size_t ws_size,
                              hipStream_t stream) {
    const float* x  = (const float*)d_in[0];
    const int*   ei = (const int*)d_in[1];
    const float* W1 = (const float*)d_in[2];
    const float* b1 = (const float*)d_in[3];
    const float* W2 = (const float*)d_in[4];
    const float* b2 = (const float*)d_in[5];
    const float* W3 = (const float*)d_in[6];
    const float* b3 = (const float*)d_in[7];
    float* out = (float*)d_out;

    const int N = in_sizes[0] / 128;
    const int E = in_sizes[1] / 2;
    const int* src = ei;
    const int* dst = ei + E;

    char* ws = (char*)d_ws;
    size_t off = 0;
    auto alloc = [&](size_t bytes) -> char* {
        char* p = ws + off;
        off = (off + bytes + 255) & ~(size_t)255;
        return p;
    };
    int nb  = (N + 255) / 256;   // reduce blocks (also dinv blocks)
    int nbE = (E + 255) / 256;
    int blocks64 = (N + 63) / 64;

    int*   deg     = (int*)alloc((size_t)N * 4);
    int*   row_off = (int*)alloc(((size_t)N + 1) * 4);
    float* dinv    = (float*)alloc((size_t)N * 4);
    int*   bsum    = (int*)alloc((size_t)nb * 4);
    int*   boff    = (int*)alloc((size_t)nb * 4);
    int*   rank    = (int*)alloc((size_t)E * 4);
    int*   csrc    = (int*)alloc((size_t)E * 4);
    unsigned short* Wt1  = (unsigned short*)alloc(128 * 128 * 2);
    unsigned short* Wt2  = (unsigned short*)alloc(128 * 128 * 2);
    unsigned short* Wt3  = (unsigned short*)alloc(64 * 128 * 2);
    unsigned short* bufA = (unsigned short*)alloc((size_t)N * 128 * 2);
    unsigned short* bufB = (unsigned short*)alloc((size_t)N * 128 * 2);
    unsigned short* bufC = (unsigned short*)alloc((size_t)N * 64 * 2);
    (void)ws_size; (void)n_in; (void)out_size;

    hipMemsetAsync(deg, 0, (size_t)N * 4, stream);
    // A: edge count/rank + W transposes
    k_count_prep<<<nbE + 160, 256, 0, stream>>>(dst, deg, rank, E, nbE, W1, W2, W3, Wt1, Wt2, Wt3);
    // B: dinv + deg block-reduce (both depend only on deg)
    k_dinv_reduce<<<nb + nb, 256, 0, stream>>>(deg, dinv, bsum, N, nb);
    // C: scan_small (block 0) + layer-1 GEMM pre-scaled by dinv
    k_scansmall_gemm1<<<1 + blocks64, 256, 0, stream>>>(bsum, boff, nb, x, Wt1, dinv, bufA, N);
    // D: final scan -> row_off
    k_scan_final<<<nb, 256, 0, stream>>>(deg, boff, row_off, N);
    // E: CSR fill (scatter only)
    k_fill<<<nbE, 256, 0, stream>>>(src, dst, rank, row_off, csrc, E);

    // layer 1 aggregation (pre-scaled bufA)
    k_agg_relu<<<((size_t)N * 16 + 255) / 256, 256, 0, stream>>>(bufA, row_off, csrc, dinv, b1, bufB, N);
    // layer 2 (epilogue scales by dinv)
    k_gemm_mfma<128><<<blocks64, 256, 0, stream>>>(bufB, Wt2, dinv, bufA, N);
    k_agg_relu<<<((size_t)N * 16 + 255) / 256, 256, 0, stream>>>(bufA, row_off, csrc, dinv, b2, bufB, N);
    // layer 3 + log_softmax
    k_gemm_mfma<64><<<blocks64, 256, 0, stream>>>(bufB, Wt3, dinv, bufC, N);
    k_agg_softmax<<<((size_t)N * 8 + 255) / 256, 256, 0, stream>>>(bufC, row_off, csrc, dinv, b3, out, N);
}